// Round 6
// baseline (467.985 us; speedup 1.0000x reference)
//
#include <hip/hip_runtime.h>

#define N_NODES 8192
#define CAP 128    // neighbor capacity; Binomial(8192,1/256): P(deg>128) ~ 0
constexpr int AST = 132;  // activation LDS row stride (floats), 16B-aligned

typedef unsigned u32x4 __attribute__((ext_vector_type(4)));
typedef unsigned short u16;
typedef __attribute__((ext_vector_type(8))) short bf16x8;
typedef __attribute__((ext_vector_type(4))) float f32x4;

// Pre-split weight fragment regions (in u16 elements): K*F each.
constexpr size_t OFF_WD  = 0;        // 128*128 = 16384
constexpr size_t OFF_WP1 = 16384;    // 256*128 = 32768
constexpr size_t OFF_WP2 = 49152;    // 128*64  = 8192
constexpr size_t OFF_WO  = 57344;    // 64*16   = 1024 (cols 8..15 zero-pad)
constexpr size_t OFF_W1  = 58368;    // 32*64   = 2048
constexpr size_t OFF_W2  = 60416;    // 64*128  = 8192
constexpr size_t OFF_WG  = 68608;    // 128*128 = 16384
constexpr size_t WTOT    = 84992;

// ---------------------------------------------------------------------------
// Kernel 1: adj scan -> CSR. One row per wave, zero barriers, chunk-level
// double buffer (proven R0 structure). SINGLE CHANGE vs R4: loads are now
// REGULAR (not nontemporal) — testing whether the NT path throttles HBM
// read BW (m13's 6.3 TB/s ceiling was measured with normal loads).
// ---------------------------------------------------------------------------
__global__ __launch_bounds__(256, 4) void scan_kernel(
    const float* __restrict__ adj, int* __restrict__ cnt,
    int* __restrict__ nbr) {
  const int t = threadIdx.x;
  const int lane = t & 63;
  const int row = blockIdx.x * 4 + (t >> 6);
  const u32x4* rowp = (const u32x4*)(adj + (size_t)row * N_NODES);
  u32x4 v[8], vn[8];
#pragma unroll
  for (int i = 0; i < 8; ++i) v[i] = rowp[i * 64 + lane];
  int running = 0;
  int* nbr_row = nbr + (size_t)row * CAP;
  for (int ch = 0; ch < 4; ++ch) {
    if (ch < 3) {  // prefetch next chunk while consuming current
      const u32x4* cp = rowp + (ch + 1) * 512;
#pragma unroll
      for (int i = 0; i < 8; ++i) vn[i] = cp[i * 64 + lane];
    }
    int c = 0;
#pragma unroll
    for (int i = 0; i < 8; ++i)
      c += (v[i].x != 0u) + (v[i].y != 0u) + (v[i].z != 0u) + (v[i].w != 0u);
    int incl = c;  // wave-inclusive prefix scan, shuffles only
#pragma unroll
    for (int s = 1; s < 64; s <<= 1) {
      int n = __shfl_up(incl, s);
      if (lane >= s) incl += n;
    }
    int off = running + incl - c;
    running += __shfl(incl, 63);
    const int colbase = ch * 2048;
#pragma unroll
    for (int i = 0; i < 8; ++i) {
      if (v[i].x | v[i].y | v[i].z | v[i].w) {
        const int col = colbase + (i * 64 + lane) * 4;
        if (v[i].x) { if (off < CAP) nbr_row[off] = col + 0; ++off; }
        if (v[i].y) { if (off < CAP) nbr_row[off] = col + 1; ++off; }
        if (v[i].z) { if (off < CAP) nbr_row[off] = col + 2; ++off; }
        if (v[i].w) { if (off < CAP) nbr_row[off] = col + 3; ++off; }
      }
    }
#pragma unroll
    for (int i = 0; i < 8; ++i) v[i] = vn[i];
  }
  if (lane == 0) cnt[row] = running;
}

// ---------------------------------------------------------------------------
// Kernel 3: agg (R0 verbatim). msg is pre-scaled by dinv.
// ---------------------------------------------------------------------------
__global__ __launch_bounds__(256) void agg_kernel(
    const int* __restrict__ cnt, const int* __restrict__ nbr,
    const float* __restrict__ msg, const float* __restrict__ bg,
    const float* __restrict__ adj, float* __restrict__ g1) {
  const int t = threadIdx.x;
  const int f = t & 127;
  const int rA = blockIdx.x * 4 + (t >> 7) * 2;
  const int rB = rA + 1;
  const int cA = cnt[rA], cB = cnt[rB];
  float a0 = msg[(size_t)rA * 128 + f];  // self-loop terms (msg pre-scaled)
  float a1 = msg[(size_t)rB * 128 + f];
  if (cA <= CAP && cB <= CAP) {
    const int* nA = nbr + (size_t)rA * CAP;
    const int* nB = nbr + (size_t)rB * CAP;
    const int cm = max(cA, cB);
    for (int i = 0; i < cm; i += 4) {
#pragma unroll
      for (int k = 0; k < 4; ++k) {
        const int ii = i + k;
        int jA = nA[ii < cA ? ii : 0] & (N_NODES - 1);
        int jB = nB[ii < cB ? ii : 0] & (N_NODES - 1);
        float vA = msg[(size_t)jA * 128 + f];
        float vB = msg[(size_t)jB * 128 + f];
        a0 += (ii < cA) ? vA : 0.f;
        a1 += (ii < cB) ? vB : 0.f;
      }
    }
  } else {  // statistically unreachable dense fallback
    a0 = msg[(size_t)rA * 128 + f];
    a1 = msg[(size_t)rB * 128 + f];
    for (int col = 0; col < N_NODES; ++col) {
      if (adj[(size_t)rA * N_NODES + col] != 0.f) a0 += msg[(size_t)col * 128 + f];
      if (adj[(size_t)rB * N_NODES + col] != 0.f) a1 += msg[(size_t)col * 128 + f];
    }
  }
  float o0 = fmaf(rsqrtf((float)cA + 1.0f), a0, bg[f]);
  float o1 = fmaf(rsqrtf((float)cB + 1.0f), a1, bg[f]);
  g1[(size_t)rA * 128 + f] = fmaxf(o0, 0.f);
  g1[(size_t)rB * 128 + f] = fmaxf(o1, 0.f);
}

// ---------------------------------------------------------------------------
// Kernel 0: pre-split ALL MLP weights into MFMA-fragment-major bf16 pairs.
// ---------------------------------------------------------------------------
__global__ __launch_bounds__(256) void prep_weights(
    const float* __restrict__ wd, const float* __restrict__ wp1,
    const float* __restrict__ wp2, const float* __restrict__ wo,
    const float* __restrict__ w1, const float* __restrict__ w2,
    const float* __restrict__ wg,
    u16* __restrict__ bh, u16* __restrict__ bl) {
  const int gid = blockIdx.x * 256 + threadIdx.x;
  if (gid >= (int)WTOT) return;
  const float* W; int K, F; size_t off; int rel; bool pad = false;
  if (gid < 16384)      { W = wd;  K = 128; F = 128; off = OFF_WD;  rel = gid; }
  else if (gid < 49152) { W = wp1; K = 256; F = 128; off = OFF_WP1; rel = gid - 16384; }
  else if (gid < 57344) { W = wp2; K = 128; F = 64;  off = OFF_WP2; rel = gid - 49152; }
  else if (gid < 58368) { W = wo;  K = 64;  F = 16;  off = OFF_WO;  rel = gid - 57344; pad = true; }
  else if (gid < 60416) { W = w1;  K = 32;  F = 64;  off = OFF_W1;  rel = gid - 58368; }
  else if (gid < 68608) { W = w2;  K = 64;  F = 128; off = OFF_W2;  rel = gid - 60416; }
  else                  { W = wg;  K = 128; F = 128; off = OFF_WG;  rel = gid - 68608; }
  const int j = rel & 7, lane = (rel >> 3) & 63, t2 = rel >> 9;
  const int nf = F >> 4;
  const int ftile = t2 % nf, kstep = t2 / nf;
  const int k = kstep * 32 + ((lane >> 4) << 3) + j;
  const int f = ftile * 16 + (lane & 15);
  const float v = (pad && f >= 8) ? 0.f : W[(size_t)f * K + k];
  const unsigned u = __float_as_uint(v);
  const unsigned uh = u & 0xffff0000u;
  const float r = v - __uint_as_float(uh);
  bh[off + rel] = (u16)(uh >> 16);
  bl[off + rel] = (u16)(__float_as_uint(r) >> 16);
}

// ---------------------------------------------------------------------------
// MFMA split-bf16 layer: one wave computes a 16-node x F output tile.
// A fragment: lane holds act[row = lane&15][k = ks*32 + (lane>>4)*8 + j].
// C/D mapping (HW-verified): col = lane&15, row = (lane>>4)*4 + r.
// D += Ahi*Bhi + Ahi*Blo + Alo*Bhi  (lo*lo ~ 2^-16 rel, dropped).
// SCALEMODE: 0 none, 1 mask[node] (with F==16: only f<8 stored), 2 dinv(cnt).
// ---------------------------------------------------------------------------
template <int K, int F, int KSPLIT, int SA, int SO, bool RELU, bool BIAS, int SCALEMODE>
__device__ __forceinline__ void mfma_layer(
    const float (*__restrict__ A0)[SA], const float (*__restrict__ A1)[SA],
    const u16* __restrict__ Bh, const u16* __restrict__ Bl,
    const float* __restrict__ bias, float (*__restrict__ O)[SO],
    float* __restrict__ gout, int gstride,
    const float* __restrict__ mask, const int* __restrict__ cntp,
    int nbase, int lane) {
  constexpr int NK = K / 32, NF = F / 16;
  f32x4 acc[NF];
  const f32x4 zz = {0.f, 0.f, 0.f, 0.f};
#pragma unroll
  for (int i = 0; i < NF; ++i) acc[i] = zz;
  const int arow = lane & 15;
  const int kgrp = (lane >> 4) << 3;
#pragma unroll
  for (int ks = 0; ks < NK; ++ks) {
    const float* ap = (ks * 32 < KSPLIT) ? &A0[arow][ks * 32 + kgrp]
                                         : &A1[arow][ks * 32 - KSPLIT + kgrp];
    const float4 p0 = *(const float4*)ap;
    const float4 p1 = *(const float4*)(ap + 4);
    const float av[8] = {p0.x, p0.y, p0.z, p0.w, p1.x, p1.y, p1.z, p1.w};
    bf16x8 ahi, alo;
#pragma unroll
    for (int j = 0; j < 8; ++j) {
      const unsigned u = __float_as_uint(av[j]);
      const unsigned uh = u & 0xffff0000u;
      const float r = av[j] - __uint_as_float(uh);
      ahi[j] = (short)(uh >> 16);
      alo[j] = (short)(__float_as_uint(r) >> 16);
    }
#pragma unroll
    for (int ft = 0; ft < NF; ++ft) {
      const size_t idx = ((size_t)(ks * NF + ft) * 64 + lane) * 8;
      const bf16x8 wh = *(const bf16x8*)(Bh + idx);
      const bf16x8 wl = *(const bf16x8*)(Bl + idx);
      acc[ft] = __builtin_amdgcn_mfma_f32_16x16x32_bf16(ahi, wh, acc[ft], 0, 0, 0);
      acc[ft] = __builtin_amdgcn_mfma_f32_16x16x32_bf16(ahi, wl, acc[ft], 0, 0, 0);
      acc[ft] = __builtin_amdgcn_mfma_f32_16x16x32_bf16(alo, wh, acc[ft], 0, 0, 0);
    }
  }
#pragma unroll
  for (int ft = 0; ft < NF; ++ft) {
    const int f = ft * 16 + (lane & 15);
    if (SCALEMODE == 1 && F == 16 && f >= 8) continue;  // zero-padded cols
    const float bv = BIAS ? bias[f] : 0.f;
#pragma unroll
    for (int r = 0; r < 4; ++r) {
      const int row = ((lane >> 4) << 2) + r;
      const int node = nbase + row;
      float v = acc[ft][r];
      if (BIAS) v += bv;
      if (RELU) v = fmaxf(v, 0.f);
      if (SCALEMODE == 1) v *= mask[node];
      if (SCALEMODE == 2) v *= rsqrtf((float)cntp[node] + 1.0f);
      if (O) O[row][f] = v;
      if (gout) gout[(size_t)node * gstride + f] = v;
    }
  }
}

// ---------------------------------------------------------------------------
// Kernel 2: MFMA encoder (R4, proven). 2 waves x 16 nodes, wave-private LDS.
// x -> h1 -> h (global) ; msg = (h @ wg.T) * dinv(cnt) (global).
// ---------------------------------------------------------------------------
__global__ __launch_bounds__(128) void mfma_encode(
    const float* __restrict__ x, const u16* __restrict__ bh,
    const u16* __restrict__ bl, const float* __restrict__ b1,
    const float* __restrict__ b2, const int* __restrict__ cnt,
    float* __restrict__ h_out, float* __restrict__ msg_out) {
  __shared__ float actX[2][16][36];
  __shared__ float actH1[2][16][68];
  __shared__ float actH[2][16][AST];
  const int t = threadIdx.x;
  const int w = t >> 6, lane = t & 63;
  const int n0 = blockIdx.x * 32 + w * 16;
#pragma unroll
  for (int i = 0; i < 2; ++i) {  // stage x: 16 rows x 8 float4
    const int fi = i * 64 + lane;
    const int row = fi >> 3, c4 = (fi & 7) * 4;
    *(float4*)&actX[w][row][c4] = *(const float4*)&x[(size_t)(n0 + row) * 32 + c4];
  }
  __syncthreads();
  mfma_layer<32, 64, 32, 36, 68, true, true, 0>(
      actX[w], actX[w], bh + OFF_W1, bl + OFF_W1, b1, actH1[w],
      nullptr, 0, nullptr, nullptr, n0, lane);
  __syncthreads();
  mfma_layer<64, 128, 64, 68, AST, true, true, 0>(
      actH1[w], actH1[w], bh + OFF_W2, bl + OFF_W2, b2, actH[w],
      h_out, 128, nullptr, nullptr, n0, lane);
  __syncthreads();
  mfma_layer<128, 128, 128, AST, AST, false, false, 2>(
      actH[w], actH[w], bh + OFF_WG, bl + OFF_WG, nullptr, (float(*)[AST])nullptr,
      msg_out, 128, nullptr, cnt, n0, lane);
}

// ---------------------------------------------------------------------------
// Kernel 4: MFMA decoder (R3/R4, proven). 2 waves x 16 nodes, wave-private
// LDS. g1 -> g2 -> p1([g2|h]) -> p2 -> out * mask.
// ---------------------------------------------------------------------------
__global__ __launch_bounds__(128) void mfma_decode(
    const float* __restrict__ g1, const float* __restrict__ h,
    const u16* __restrict__ bh, const u16* __restrict__ bl,
    const float* __restrict__ bd, const float* __restrict__ bp1,
    const float* __restrict__ bp2, const float* __restrict__ bo,
    const float* __restrict__ mask, float* __restrict__ out) {
  __shared__ float actA[2][16][AST];
  __shared__ float actB[2][16][AST];
  __shared__ float actH[2][16][AST];
  const int t = threadIdx.x;
  const int w = t >> 6, lane = t & 63;
  const int n0 = blockIdx.x * 32 + w * 16;
#pragma unroll
  for (int i = 0; i < 8; ++i) {  // stage g1 + h: 16 rows x 32 float4 each
    const int fi = i * 64 + lane;
    const int row = fi >> 5, c4 = (fi & 31) * 4;
    *(float4*)&actA[w][row][c4] = *(const float4*)&g1[(size_t)(n0 + row) * 128 + c4];
    *(float4*)&actH[w][row][c4] = *(const float4*)&h[(size_t)(n0 + row) * 128 + c4];
  }
  __syncthreads();
  mfma_layer<128, 128, 128, AST, AST, true, true, 0>(
      actA[w], actA[w], bh + OFF_WD, bl + OFF_WD, bd, actB[w],
      nullptr, 0, nullptr, nullptr, n0, lane);
  __syncthreads();
  mfma_layer<256, 128, 128, AST, AST, true, true, 0>(
      actB[w], actH[w], bh + OFF_WP1, bl + OFF_WP1, bp1, actA[w],
      nullptr, 0, nullptr, nullptr, n0, lane);
  __syncthreads();
  mfma_layer<128, 64, 128, AST, AST, true, true, 0>(
      actA[w], actA[w], bh + OFF_WP2, bl + OFF_WP2, bp2, actB[w],
      nullptr, 0, nullptr, nullptr, n0, lane);
  __syncthreads();
  mfma_layer<64, 16, 128, AST, AST, false, true, 1>(
      actB[w], actB[w], bh + OFF_WO, bl + OFF_WO, bo, (float(*)[AST])nullptr,
      out, 8, mask, nullptr, n0, lane);
}

extern "C" void kernel_launch(void* const* d_in, const int* in_sizes, int n_in,
                              void* d_out, int out_size, void* d_ws, size_t ws_size,
                              hipStream_t stream) {
  const float* x    = (const float*)d_in[0];
  const float* adj  = (const float*)d_in[1];
  const float* mask = (const float*)d_in[2];
  const float* w1   = (const float*)d_in[3];
  const float* b1   = (const float*)d_in[4];
  const float* w2   = (const float*)d_in[5];
  const float* b2   = (const float*)d_in[6];
  const float* wg   = (const float*)d_in[7];
  const float* bg   = (const float*)d_in[8];
  const float* wd   = (const float*)d_in[9];
  const float* bd   = (const float*)d_in[10];
  const float* wp1  = (const float*)d_in[11];
  const float* bp1  = (const float*)d_in[12];
  const float* wp2  = (const float*)d_in[13];
  const float* bp2  = (const float*)d_in[14];
  const float* wo   = (const float*)d_in[15];
  const float* bo   = (const float*)d_in[16];
  float* out = (float*)d_out;

  float* ws = (float*)d_ws;
  float* h    = ws; ws += (size_t)N_NODES * 128;
  float* msg  = ws; ws += (size_t)N_NODES * 128;
  float* g1   = ws; ws += (size_t)N_NODES * 128;
  int* cnt = (int*)ws; ws += N_NODES;
  int* nbr = (int*)ws; ws += (size_t)N_NODES * CAP;
  u16* bh = (u16*)ws;
  u16* bl = bh + WTOT;

  prep_weights<<<(int)((WTOT + 255) / 256), 256, 0, stream>>>(
      wd, wp1, wp2, wo, w1, w2, wg, bh, bl);
  scan_kernel<<<N_NODES / 4, 256, 0, stream>>>(adj, cnt, nbr);
  mfma_encode<<<N_NODES / 32, 128, 0, stream>>>(x, bh, bl, b1, b2, cnt, h, msg);
  agg_kernel<<<N_NODES / 4, 256, 0, stream>>>(cnt, nbr, msg, bg, adj, g1);
  mfma_decode<<<N_NODES / 32, 128, 0, stream>>>(g1, h, bh, bl, bd, bp1, bp2, bo, mask, out);
}